// Round 2
// baseline (1192.217 us; speedup 1.0000x reference)
//
#include <hip/hip_runtime.h>
#include <cstddef>
#include <cstdint>

typedef __attribute__((ext_vector_type(8))) _Float16 half8;
typedef __attribute__((ext_vector_type(4))) float f32x4;
typedef _Float16 half_t;

#define NS 16
#define NN 32

// ---------------- workspace layout (bytes) ----------------
// h1p : f16 [n][s][64][66][32]  (x-padded, pre-BN)  = 138412032
// h2p : f16 [n][s][64][66][64]                      = 276824064
// zr1 : f16 [s][66][32] pad-row                      = 67584
// zr2 : f16 [s][66][64]                              = 135168
// wt1 : f32 [s][3][9][32]                            = 55296
// wt2 : f16 [s][9][64][32]  (BN1 scale folded)       = 589824
// wt3 : f16 [s][9][64][64]  (BN2 scale folded)       = 1179648
// sums: f32 5120                                     = 20480
// prm : f32 7680 (a1,b1,t1,a2,b2,t2,a3,b3,t3)        = 30720
// th  : f16 2560 (t1h,t2h,t3h)                       = 5120
static const size_t OFF_H1P = 0;
static const size_t OFF_H2P = 138412032ull;
static const size_t OFF_ZR1 = OFF_H2P + 276824064ull;   // 415236096
static const size_t OFF_ZR2 = OFF_ZR1 + 67584ull;       // 415303680
static const size_t OFF_WT1 = OFF_ZR2 + 135168ull;      // 415438848
static const size_t OFF_WT2 = OFF_WT1 + 55296ull;       // 415494144
static const size_t OFF_WT3 = OFF_WT2 + 589824ull;      // 416083968
static const size_t OFF_SUMS = OFF_WT3 + 1179648ull;    // 417263616
static const size_t OFF_PRM = OFF_SUMS + 20480ull;      // 417284096
static const size_t OFF_TH  = OFF_PRM + 30720ull;       // 417314816
// total ~417.3 MB

static __device__ __forceinline__ half8 sr8(half8 v, half8 t) {
    half8 r = v + t;
    half8 z = {};
#if defined(__has_builtin) && __has_builtin(__builtin_elementwise_max)
    return __builtin_elementwise_max(r, z);
#else
#pragma unroll
    for (int j = 0; j < 8; ++j) r[j] = r[j] > (_Float16)0 ? r[j] : (_Float16)0;
    return r;
#endif
}

// -------- conv1 weights: oc-contiguous f32 --------
__global__ __launch_bounds__(256) void transform1_k(
    const float* __restrict__ w1, float* __restrict__ wt1)
{
    int idx = blockIdx.x * 256 + threadIdx.x;
    if (idx >= 13824) return;
    int o = idx & 31, tap = (idx >> 5) % 9, ic = (idx / 288) % 3, s = idx / 864;
    wt1[idx] = w1[((s * 32 + o) * 3 + ic) * 9 + tap];
}

// -------- conv2/conv3 weights: ic-contiguous f16, BN scale of previous layer folded --------
__global__ __launch_bounds__(256) void wtrans2_k(
    const float* __restrict__ w2, const float* __restrict__ a1, half_t* __restrict__ wt2)
{
    int idx = blockIdx.x * 256 + threadIdx.x;
    if (idx >= 294912) return;
    int ic = idx & 31, oc = (idx >> 5) & 63, tap = (idx >> 11) % 9, s = idx / 18432;
    wt2[idx] = (half_t)(w2[((s * 64 + oc) * 32 + ic) * 9 + tap] * a1[s * 32 + ic]);
}

__global__ __launch_bounds__(256) void wtrans3_k(
    const float* __restrict__ w3, const float* __restrict__ a2, half_t* __restrict__ wt3)
{
    int idx = blockIdx.x * 256 + threadIdx.x;
    if (idx >= 589824) return;
    int ic = idx & 63, oc = (idx >> 6) & 63, tap = (idx >> 12) % 9, s = idx / 36864;
    wt3[idx] = (half_t)(w3[((s * 64 + oc) * 64 + ic) * 9 + tap] * a2[s * 64 + ic]);
}

// -------- conv1: 3->32 per seed, fp32 vector math, writes x-padded h1p (pre-BN) + stats --------
__global__ __launch_bounds__(256) void conv1_k(
    const float* __restrict__ x, const float* __restrict__ wt1,
    const float* __restrict__ b1, half_t* __restrict__ h1p,
    float* __restrict__ sums1)
{
    __shared__ float smem[8512];
    float* xt = smem;
    float* bounce = smem;
    float* statsl = smem + 8448;
    const int tile = blockIdx.x, s = blockIdx.y, n = blockIdx.z;
    const int tx = tile & 3, ty = tile >> 2, tid = threadIdx.x;

    for (int i = tid; i < 972; i += 256) {
        int ic = i / 324, rem = i - ic * 324;
        int py = rem / 18, px = rem - py * 18;
        int gy = ty * 16 + py - 1, gx = tx * 16 + px - 1;
        float v = 0.f;
        if ((unsigned)gy < 64u && (unsigned)gx < 64u)
            v = x[(size_t)(((s * NN + n) * 3 + ic) * 64 + gy) * 64 + gx];
        xt[i] = v;
    }
    if (tid < 64) statsl[tid] = 0.f;
    __syncthreads();

    const int px = tid & 15, py = tid >> 4;
    float acc[32];
#pragma unroll
    for (int o = 0; o < 32; ++o) acc[o] = 0.f;
#pragma unroll
    for (int ic = 0; ic < 3; ++ic)
#pragma unroll
        for (int ky = 0; ky < 3; ++ky)
#pragma unroll
            for (int kx = 0; kx < 3; ++kx) {
                float v = xt[ic * 324 + (py + ky) * 18 + px + kx];
                const float* wp = wt1 + ((s * 3 + ic) * 9 + ky * 3 + kx) * 32;
#pragma unroll
                for (int o = 0; o < 32; ++o) acc[o] = fmaf(wp[o], v, acc[o]);
            }
    const float* bp = b1 + s * 32;
#pragma unroll
    for (int o = 0; o < 32; ++o) acc[o] += bp[o];

    const int gy1 = ty * 16 + py, gxp = tx * 16 + px + 1;
    half8* dst = (half8*)(h1p + (size_t)(n * NS + s) * 135168 + (size_t)(gy1 * 66 + gxp) * 32);
#pragma unroll
    for (int k = 0; k < 4; ++k) {
        half8 v8;
#pragma unroll
        for (int j = 0; j < 8; ++j) v8[j] = (half_t)acc[k * 8 + j];
        dst[k] = v8;
    }
    __syncthreads();
#pragma unroll
    for (int o = 0; o < 32; ++o) bounce[tid * 33 + o] = acc[o];
    __syncthreads();
    {
        const int oc = tid & 31, grp = tid >> 5;
        float s1 = 0.f, s2 = 0.f;
#pragma unroll 4
        for (int j = 0; j < 32; ++j) {
            float v = bounce[(grp * 32 + j) * 33 + oc];
            s1 += v; s2 += v * v;
        }
        atomicAdd(&statsl[oc * 2], s1);
        atomicAdd(&statsl[oc * 2 + 1], s2);
    }
    __syncthreads();
    if (tid < 64)
        atomicAdd(&sums1[(s * 32 + (tid >> 1)) * 2 + (tid & 1)], statsl[tid]);
}

// -------- sums -> scale a, shift b, pre-act shift t = b/a (and f16 copy) --------
__global__ void bnparam_k(const float* __restrict__ sums, const float* __restrict__ g,
                          const float* __restrict__ be, float* __restrict__ a,
                          float* __restrict__ b, float* __restrict__ t,
                          half_t* __restrict__ th, int C)
{
    int ch = blockIdx.x * 256 + threadIdx.x;
    if (ch >= C) return;
    const float inv = 1.f / 131072.f;     // N*H*W = 32*64*64
    float mean = sums[ch * 2] * inv;
    float var = sums[ch * 2 + 1] * inv - mean * mean;
    float sc = g[ch] * rsqrtf(var + 1e-5f);
    a[ch] = sc;
    float bb = be[ch] - mean * sc;
    b[ch] = bb;
    float tt = bb / sc;
    t[ch] = tt;
    th[ch] = (half_t)tt;
}

// -------- fill pad columns + pad row with q = -(t+1), so relu(q + t) == 0 --------
__global__ __launch_bounds__(256) void padfill_k(
    half_t* __restrict__ img, half_t* __restrict__ zrow, const float* __restrict__ t,
    int C, int c8shift, long imgstride, int rowstride, long tot_cols, long tot)
{
    long idx = (long)blockIdx.x * 256 + threadIdx.x;
    if (idx >= tot) return;
    const int nc8m = (1 << c8shift) - 1;
    if (idx < tot_cols) {
        int c8 = (int)idx & nc8m; long r = idx >> c8shift;
        int side = (int)r & 1; r >>= 1;
        int y = (int)r & 63; r >>= 6;
        int si = (int)(r & 15); int ni = (int)(r >> 4);
        half8 q;
#pragma unroll
        for (int j = 0; j < 8; ++j) q[j] = (half_t)(-(t[si * C + c8 * 8 + j] + 1.0f));
        *(half8*)(img + (long)(ni * NS + si) * imgstride + (long)y * rowstride +
                  (side ? 65 : 0) * C + c8 * 8) = q;
    } else {
        long r2 = idx - tot_cols;
        int c8 = (int)r2 & nc8m; r2 >>= c8shift;
        int xx = (int)(r2 % 66); int si = (int)(r2 / 66);
        half8 q;
#pragma unroll
        for (int j = 0; j < 8; ++j) q[j] = (half_t)(-(t[si * C + c8 * 8 + j] + 1.0f));
        *(half8*)(zrow + ((long)(si * 66 + xx)) * C + c8 * 8) = q;
    }
}

// -------- conv2: 32->64, direct global A-frags, shift-relu inline, LDS only for output bounce --------
__global__ __launch_bounds__(256, 4) void conv2_k(
    const half_t* __restrict__ h1p, const half_t* __restrict__ zr1,
    const half_t* __restrict__ wt2, const float* __restrict__ b2,
    const half_t* __restrict__ th1, half_t* __restrict__ h2p,
    float* __restrict__ sums2)
{
    __shared__ __align__(16) half_t obuf[256 * 72];   // 36 KB, 72-stride vs bank conflicts
    __shared__ float statsl[128];
    const int tile = blockIdx.x, s = blockIdx.y, n = blockIdx.z;
    const int tx = tile & 3, ty = tile >> 2, tid = threadIdx.x;
    const int l = tid & 63, wv = tid >> 6, l15 = l & 15, g = l >> 4;
    if (tid < 128) statsl[tid] = 0.f;
    __syncthreads();

    const half_t* img = h1p + (size_t)(n * NS + s) * 135168;
    const half_t* zrow = zr1 + s * 2112;
    const half8 tsh = *(const half8*)(th1 + s * 32 + g * 8);
    const half_t* wb = wt2 + (size_t)s * 18432;
    const int laneoff = l15 * 32 + g * 8;

    f32x4 acc[4][4];
#pragma unroll
    for (int mt = 0; mt < 4; ++mt)
#pragma unroll
        for (int nt = 0; nt < 4; ++nt) acc[mt][nt] = (f32x4){0.f, 0.f, 0.f, 0.f};

#pragma unroll 1
    for (int tap = 0; tap < 9; ++tap) {
        const int ky = tap / 3, kx = tap - ky * 3;
        half8 bf[4];
#pragma unroll
        for (int nt = 0; nt < 4; ++nt)
            bf[nt] = *(const half8*)(wb + (tap * 64 + nt * 16 + l15) * 32 + g * 8);
        const int xb = (tx * 16 + kx) * 32;
#pragma unroll
        for (int mt = 0; mt < 4; ++mt) {
            const int gy = ty * 16 + wv * 4 + mt + ky - 1;
            const half_t* rp = zrow;
            if ((unsigned)gy < 64u) rp = img + gy * 2112;
            half8 av = sr8(*(const half8*)(rp + xb + laneoff), tsh);
#pragma unroll
            for (int nt = 0; nt < 4; ++nt)
                acc[mt][nt] = __builtin_amdgcn_mfma_f32_16x16x32_f16(av, bf[nt], acc[mt][nt], 0, 0, 0);
        }
    }

    float s1a[4], s2a[4];
#pragma unroll
    for (int nt = 0; nt < 4; ++nt) {
        float bias = b2[s * 64 + nt * 16 + l15];
        float s1 = 0.f, s2 = 0.f;
#pragma unroll
        for (int mt = 0; mt < 4; ++mt)
#pragma unroll
            for (int r = 0; r < 4; ++r) {
                float v = acc[mt][nt][r] + bias;
                acc[mt][nt][r] = v;
                s1 += v; s2 += v * v;
            }
        s1 += __shfl_xor(s1, 16); s1 += __shfl_xor(s1, 32);
        s2 += __shfl_xor(s2, 16); s2 += __shfl_xor(s2, 32);
        s1a[nt] = s1; s2a[nt] = s2;
    }
    if (l < 16) {
#pragma unroll
        for (int nt = 0; nt < 4; ++nt) {
            atomicAdd(&statsl[(nt * 16 + l15) * 2], s1a[nt]);
            atomicAdd(&statsl[(nt * 16 + l15) * 2 + 1], s2a[nt]);
        }
    }

#pragma unroll
    for (int mt = 0; mt < 4; ++mt)
#pragma unroll
        for (int nt = 0; nt < 4; ++nt)
#pragma unroll
            for (int r = 0; r < 4; ++r)
                obuf[((wv * 4 + mt) * 16 + g * 4 + r) * 72 + nt * 16 + l15] = (half_t)acc[mt][nt][r];
    __syncthreads();

    half_t* img2 = h2p + (size_t)(n * NS + s) * 270336;
    for (int i = tid; i < 2048; i += 256) {
        int p = i >> 3, cc = i & 7;
        int y = ty * 16 + (p >> 4), xp = tx * 16 + (p & 15) + 1;
        *(half8*)(img2 + (size_t)y * 4224 + xp * 64 + cc * 8) = *(const half8*)(obuf + p * 72 + cc * 8);
    }
    if (tid < 128)
        atomicAdd(&sums2[(s * 64 + (tid >> 1)) * 2 + (tid & 1)], statsl[tid]);
}

// -------- conv3: 64->64, direct global A-frags, no LDS except stats; pre-BN fp32 to d_out --------
__global__ __launch_bounds__(256, 3) void conv3_k(
    const half_t* __restrict__ h2p, const half_t* __restrict__ zr2,
    const half_t* __restrict__ wt3, const float* __restrict__ b3,
    const half_t* __restrict__ th2, float* __restrict__ out,
    float* __restrict__ sums3)
{
    __shared__ float statsl[128];
    const int tile = blockIdx.x, s = blockIdx.y, n = blockIdx.z;
    const int tx = tile & 3, ty = tile >> 2, tid = threadIdx.x;
    const int l = tid & 63, wv = tid >> 6, l15 = l & 15, g = l >> 4;
    if (tid < 128) statsl[tid] = 0.f;
    __syncthreads();

    const half_t* img = h2p + (size_t)(n * NS + s) * 270336;
    const half_t* zrow = zr2 + s * 4224;
    const half8 tsh0 = *(const half8*)(th2 + s * 64 + g * 8);
    const half8 tsh1 = *(const half8*)(th2 + s * 64 + 32 + g * 8);
    const half_t* wb = wt3 + (size_t)s * 36864;
    const int laneoff = l15 * 64 + g * 8;

    f32x4 acc[4][4];
#pragma unroll
    for (int mt = 0; mt < 4; ++mt)
#pragma unroll
        for (int nt = 0; nt < 4; ++nt) acc[mt][nt] = (f32x4){0.f, 0.f, 0.f, 0.f};

#pragma unroll 1
    for (int tap = 0; tap < 9; ++tap) {
        const int ky = tap / 3, kx = tap - ky * 3;
        half8 bf0[4], bf1[4];
#pragma unroll
        for (int nt = 0; nt < 4; ++nt) {
            bf0[nt] = *(const half8*)(wb + (tap * 64 + nt * 16 + l15) * 64 + g * 8);
            bf1[nt] = *(const half8*)(wb + (tap * 64 + nt * 16 + l15) * 64 + 32 + g * 8);
        }
        const int xb = (tx * 16 + kx) * 64;
#pragma unroll
        for (int mt = 0; mt < 4; ++mt) {
            const int gy = ty * 16 + wv * 4 + mt + ky - 1;
            const half_t* rp = zrow;
            if ((unsigned)gy < 64u) rp = img + gy * 4224;
            half8 a0 = sr8(*(const half8*)(rp + xb + laneoff), tsh0);
            half8 a1 = sr8(*(const half8*)(rp + xb + laneoff + 32), tsh1);
#pragma unroll
            for (int nt = 0; nt < 4; ++nt) {
                acc[mt][nt] = __builtin_amdgcn_mfma_f32_16x16x32_f16(a0, bf0[nt], acc[mt][nt], 0, 0, 0);
                acc[mt][nt] = __builtin_amdgcn_mfma_f32_16x16x32_f16(a1, bf1[nt], acc[mt][nt], 0, 0, 0);
            }
        }
    }

    float s1a[4], s2a[4];
#pragma unroll
    for (int nt = 0; nt < 4; ++nt) {
        float bias = b3[s * 64 + nt * 16 + l15];
        float s1 = 0.f, s2 = 0.f;
#pragma unroll
        for (int mt = 0; mt < 4; ++mt)
#pragma unroll
            for (int r = 0; r < 4; ++r) {
                float v = acc[mt][nt][r] + bias;
                acc[mt][nt][r] = v;
                s1 += v; s2 += v * v;
            }
        s1 += __shfl_xor(s1, 16); s1 += __shfl_xor(s1, 32);
        s2 += __shfl_xor(s2, 16); s2 += __shfl_xor(s2, 32);
        s1a[nt] = s1; s2a[nt] = s2;
    }
    if (l < 16) {
#pragma unroll
        for (int nt = 0; nt < 4; ++nt) {
            atomicAdd(&statsl[(nt * 16 + l15) * 2], s1a[nt]);
            atomicAdd(&statsl[(nt * 16 + l15) * 2 + 1], s2a[nt]);
        }
    }

#pragma unroll
    for (int mt = 0; mt < 4; ++mt) {
        int gy = ty * 16 + wv * 4 + mt;
#pragma unroll
        for (int nt = 0; nt < 4; ++nt) {
            int c = nt * 16 + l15;
            *(f32x4*)(out + ((size_t)((s * NN + n) * 64 + c) * 64 + gy) * 64 + tx * 16 + g * 4) = acc[mt][nt];
        }
    }
    __syncthreads();
    if (tid < 128)
        atomicAdd(&sums3[(s * 64 + (tid >> 1)) * 2 + (tid & 1)], statsl[tid]);
}

// -------- final: in-place BN3+ReLU on d_out --------
__global__ __launch_bounds__(256) void final_k(float* __restrict__ out,
                                               const float* __restrict__ a3,
                                               const float* __restrict__ b3p)
{
    size_t i = ((size_t)blockIdx.x * 256 + threadIdx.x) * 4;
    int ch = (int)((i >> 12) & 63) + (int)(i >> 23) * 64; // c + s*64
    float sc = a3[ch], sh = b3p[ch];
    f32x4 v = *(f32x4*)(out + i);
#pragma unroll
    for (int r = 0; r < 4; ++r) v[r] = fmaxf(fmaf(sc, v[r], sh), 0.f);
    *(f32x4*)(out + i) = v;
}

extern "C" void kernel_launch(void* const* d_in, const int* in_sizes, int n_in,
                              void* d_out, int out_size, void* d_ws, size_t ws_size,
                              hipStream_t stream)
{
    const float* x   = (const float*)d_in[0];
    const float* w1  = (const float*)d_in[1];
    const float* b1  = (const float*)d_in[2];
    const float* g1  = (const float*)d_in[3];
    const float* be1 = (const float*)d_in[4];
    const float* w2  = (const float*)d_in[5];
    const float* b2  = (const float*)d_in[6];
    const float* g2  = (const float*)d_in[7];
    const float* be2 = (const float*)d_in[8];
    const float* w3  = (const float*)d_in[9];
    const float* b3  = (const float*)d_in[10];
    const float* g3  = (const float*)d_in[11];
    const float* be3 = (const float*)d_in[12];

    char* ws = (char*)d_ws;
    half_t* h1p = (half_t*)(ws + OFF_H1P);
    half_t* h2p = (half_t*)(ws + OFF_H2P);
    half_t* zr1 = (half_t*)(ws + OFF_ZR1);
    half_t* zr2 = (half_t*)(ws + OFF_ZR2);
    float*  wt1 = (float*)(ws + OFF_WT1);
    half_t* wt2 = (half_t*)(ws + OFF_WT2);
    half_t* wt3 = (half_t*)(ws + OFF_WT3);
    float*  sums = (float*)(ws + OFF_SUMS);
    float *s1v = sums, *s2v = sums + 1024, *s3v = sums + 3072;
    float*  prm = (float*)(ws + OFF_PRM);
    float *a1 = prm,        *b1p = prm + 512,  *t1 = prm + 1024;
    float *a2 = prm + 1536, *b2p = prm + 2560, *t2 = prm + 3584;
    float *a3 = prm + 4608, *b3p = prm + 5632, *t3 = prm + 6656;
    half_t* th = (half_t*)(ws + OFF_TH);
    half_t *th1 = th, *th2 = th + 512, *th3 = th + 1536;
    float* out = (float*)d_out;

    hipMemsetAsync(ws + OFF_SUMS, 0, 20480, stream);
    transform1_k<<<54, 256, 0, stream>>>(w1, wt1);
    dim3 grid(16, 16, 32); // (tile, seed, sample)
    conv1_k<<<grid, 256, 0, stream>>>(x, wt1, b1, h1p, s1v);
    bnparam_k<<<2, 256, 0, stream>>>(s1v, g1, be1, a1, b1p, t1, th1, 512);
    padfill_k<<<1041, 256, 0, stream>>>(h1p, zr1, t1, 32, 2, 135168L, 2112, 262144L, 266368L);
    wtrans2_k<<<1152, 256, 0, stream>>>(w2, a1, wt2);
    conv2_k<<<grid, 256, 0, stream>>>(h1p, zr1, wt2, b2, th1, h2p, s2v);
    bnparam_k<<<4, 256, 0, stream>>>(s2v, g2, be2, a2, b2p, t2, th2, 1024);
    padfill_k<<<2081, 256, 0, stream>>>(h2p, zr2, t2, 64, 3, 270336L, 4224, 524288L, 532736L);
    wtrans3_k<<<2304, 256, 0, stream>>>(w3, a2, wt3);
    conv3_k<<<grid, 256, 0, stream>>>(h2p, zr2, wt3, b3, th2, out, s3v);
    bnparam_k<<<4, 256, 0, stream>>>(s3v, g3, be3, a3, b3p, t3, th3, 1024);
    final_k<<<131072, 256, 0, stream>>>(out, a3, b3p);
}

// Round 3
// 1001.581 us; speedup vs baseline: 1.1903x; 1.1903x over previous
//
#include <hip/hip_runtime.h>
#include <cstddef>
#include <cstdint>

typedef __attribute__((ext_vector_type(8))) _Float16 half8;
typedef __attribute__((ext_vector_type(4))) float f32x4;
typedef _Float16 half_t;

#define NS 16
#define NN 32

// ---------------- workspace layout (bytes) ----------------
static const size_t OFF_H1P = 0;
static const size_t OFF_H2P = 138412032ull;
static const size_t OFF_ZR1 = OFF_H2P + 276824064ull;   // 415236096
static const size_t OFF_ZR2 = OFF_ZR1 + 67584ull;       // 415303680
static const size_t OFF_WT1 = OFF_ZR2 + 135168ull;      // 415438848
static const size_t OFF_WT2 = OFF_WT1 + 55296ull;       // 415494144
static const size_t OFF_WT3 = OFF_WT2 + 589824ull;      // 416083968
static const size_t OFF_SUMS = OFF_WT3 + 1179648ull;    // 417263616
static const size_t OFF_PRM = OFF_SUMS + 20480ull;      // 417284096
static const size_t OFF_TH  = OFF_PRM + 30720ull;       // 417314816

static __device__ __forceinline__ half8 sr8(half8 v, half8 t) {
    half8 r = v + t;
    half8 z = {};
#if defined(__has_builtin) && __has_builtin(__builtin_elementwise_max)
    return __builtin_elementwise_max(r, z);
#else
#pragma unroll
    for (int j = 0; j < 8; ++j) r[j] = r[j] > (_Float16)0 ? r[j] : (_Float16)0;
    return r;
#endif
}

// -------- conv1 weights: oc-contiguous f32 --------
__global__ __launch_bounds__(256) void transform1_k(
    const float* __restrict__ w1, float* __restrict__ wt1)
{
    int idx = blockIdx.x * 256 + threadIdx.x;
    if (idx >= 13824) return;
    int o = idx & 31, tap = (idx >> 5) % 9, ic = (idx / 288) % 3, s = idx / 864;
    wt1[idx] = w1[((s * 32 + o) * 3 + ic) * 9 + tap];
}

// -------- conv2/conv3 weights: ic-contiguous f16, BN scale of previous layer folded --------
__global__ __launch_bounds__(256) void wtrans2_k(
    const float* __restrict__ w2, const float* __restrict__ a1, half_t* __restrict__ wt2)
{
    int idx = blockIdx.x * 256 + threadIdx.x;
    if (idx >= 294912) return;
    int ic = idx & 31, oc = (idx >> 5) & 63, tap = (idx >> 11) % 9, s = idx / 18432;
    wt2[idx] = (half_t)(w2[((s * 64 + oc) * 32 + ic) * 9 + tap] * a1[s * 32 + ic]);
}

__global__ __launch_bounds__(256) void wtrans3_k(
    const float* __restrict__ w3, const float* __restrict__ a2, half_t* __restrict__ wt3)
{
    int idx = blockIdx.x * 256 + threadIdx.x;
    if (idx >= 589824) return;
    int ic = idx & 63, oc = (idx >> 6) & 63, tap = (idx >> 12) % 9, s = idx / 36864;
    wt3[idx] = (half_t)(w3[((s * 64 + oc) * 64 + ic) * 9 + tap] * a2[s * 64 + ic]);
}

// -------- conv1: 3->32 per seed, fp32 vector math, writes x-padded h1p (pre-BN) + stats --------
__global__ __launch_bounds__(256) void conv1_k(
    const float* __restrict__ x, const float* __restrict__ wt1,
    const float* __restrict__ b1, half_t* __restrict__ h1p,
    float* __restrict__ sums1)
{
    __shared__ float smem[8512];
    float* xt = smem;
    float* bounce = smem;
    float* statsl = smem + 8448;
    const int tile = blockIdx.x, s = blockIdx.y, n = blockIdx.z;
    const int tx = tile & 3, ty = tile >> 2, tid = threadIdx.x;

    for (int i = tid; i < 972; i += 256) {
        int ic = i / 324, rem = i - ic * 324;
        int py = rem / 18, px = rem - py * 18;
        int gy = ty * 16 + py - 1, gx = tx * 16 + px - 1;
        float v = 0.f;
        if ((unsigned)gy < 64u && (unsigned)gx < 64u)
            v = x[(size_t)(((s * NN + n) * 3 + ic) * 64 + gy) * 64 + gx];
        xt[i] = v;
    }
    if (tid < 64) statsl[tid] = 0.f;
    __syncthreads();

    const int px = tid & 15, py = tid >> 4;
    float acc[32];
#pragma unroll
    for (int o = 0; o < 32; ++o) acc[o] = 0.f;
#pragma unroll
    for (int ic = 0; ic < 3; ++ic)
#pragma unroll
        for (int ky = 0; ky < 3; ++ky)
#pragma unroll
            for (int kx = 0; kx < 3; ++kx) {
                float v = xt[ic * 324 + (py + ky) * 18 + px + kx];
                const float* wp = wt1 + ((s * 3 + ic) * 9 + ky * 3 + kx) * 32;
#pragma unroll
                for (int o = 0; o < 32; ++o) acc[o] = fmaf(wp[o], v, acc[o]);
            }
    const float* bp = b1 + s * 32;
#pragma unroll
    for (int o = 0; o < 32; ++o) acc[o] += bp[o];

    const int gy1 = ty * 16 + py, gxp = tx * 16 + px + 1;
    half8* dst = (half8*)(h1p + (size_t)(n * NS + s) * 135168 + (size_t)(gy1 * 66 + gxp) * 32);
#pragma unroll
    for (int k = 0; k < 4; ++k) {
        half8 v8;
#pragma unroll
        for (int j = 0; j < 8; ++j) v8[j] = (half_t)acc[k * 8 + j];
        dst[k] = v8;
    }
    __syncthreads();
#pragma unroll
    for (int o = 0; o < 32; ++o) bounce[tid * 33 + o] = acc[o];
    __syncthreads();
    {
        const int oc = tid & 31, grp = tid >> 5;
        float s1 = 0.f, s2 = 0.f;
#pragma unroll 4
        for (int j = 0; j < 32; ++j) {
            float v = bounce[(grp * 32 + j) * 33 + oc];
            s1 += v; s2 += v * v;
        }
        atomicAdd(&statsl[oc * 2], s1);
        atomicAdd(&statsl[oc * 2 + 1], s2);
    }
    __syncthreads();
    if (tid < 64)
        atomicAdd(&sums1[(s * 32 + (tid >> 1)) * 2 + (tid & 1)], statsl[tid]);
}

// -------- sums -> scale a, shift b, pre-act shift t = b/a (and f16 copy) --------
__global__ void bnparam_k(const float* __restrict__ sums, const float* __restrict__ g,
                          const float* __restrict__ be, float* __restrict__ a,
                          float* __restrict__ b, float* __restrict__ t,
                          half_t* __restrict__ th, int C)
{
    int ch = blockIdx.x * 256 + threadIdx.x;
    if (ch >= C) return;
    const float inv = 1.f / 131072.f;     // N*H*W = 32*64*64
    float mean = sums[ch * 2] * inv;
    float var = sums[ch * 2 + 1] * inv - mean * mean;
    float sc = g[ch] * rsqrtf(var + 1e-5f);
    a[ch] = sc;
    float bb = be[ch] - mean * sc;
    b[ch] = bb;
    float tt = bb / sc;
    t[ch] = tt;
    th[ch] = (half_t)tt;
}

// -------- fill pad columns + pad row with q = -(t+1), so relu(q + t) == 0 --------
__global__ __launch_bounds__(256) void padfill_k(
    half_t* __restrict__ img, half_t* __restrict__ zrow, const float* __restrict__ t,
    int C, int c8shift, long imgstride, int rowstride, long tot_cols, long tot)
{
    long idx = (long)blockIdx.x * 256 + threadIdx.x;
    if (idx >= tot) return;
    const int nc8m = (1 << c8shift) - 1;
    if (idx < tot_cols) {
        int c8 = (int)idx & nc8m; long r = idx >> c8shift;
        int side = (int)r & 1; r >>= 1;
        int y = (int)r & 63; r >>= 6;
        int si = (int)(r & 15); int ni = (int)(r >> 4);
        half8 q;
#pragma unroll
        for (int j = 0; j < 8; ++j) q[j] = (half_t)(-(t[si * C + c8 * 8 + j] + 1.0f));
        *(half8*)(img + (long)(ni * NS + si) * imgstride + (long)y * rowstride +
                  (side ? 65 : 0) * C + c8 * 8) = q;
    } else {
        long r2 = idx - tot_cols;
        int c8 = (int)r2 & nc8m; r2 >>= c8shift;
        int xx = (int)(r2 % 66); int si = (int)(r2 / 66);
        half8 q;
#pragma unroll
        for (int j = 0; j < 8; ++j) q[j] = (half_t)(-(t[si * C + c8 * 8 + j] + 1.0f));
        *(half8*)(zrow + ((long)(si * 66 + xx)) * C + c8 * 8) = q;
    }
}

// ======== conv2: LDS A-tile (80B px stride), B via register prefetch ========
__device__ __forceinline__ void loadB2(half8 bf[4], const half_t* wb, int tap, int l15, int g) {
#pragma unroll
    for (int nt = 0; nt < 4; ++nt)
        bf[nt] = *(const half8*)(wb + (tap * 64 + nt * 16 + l15) * 32 + g * 8);
}

__device__ __forceinline__ void comp2(f32x4 acc[4][4], const half8 bf[4], const char* smem,
                                      int tap, int wv, int l15, int g) {
    const int ky = tap / 3, kx = tap - ky * 3;
#pragma unroll
    for (int mt = 0; mt < 4; ++mt) {
        int p = (wv * 4 + mt + ky) * 18 + l15 + kx;
        half8 av = *(const half8*)(smem + p * 80 + g * 16);
#pragma unroll
        for (int nt = 0; nt < 4; ++nt)
            acc[mt][nt] = __builtin_amdgcn_mfma_f32_16x16x32_f16(av, bf[nt], acc[mt][nt], 0, 0, 0);
    }
}

__global__ __launch_bounds__(256, 3) void conv2_k(
    const half_t* __restrict__ h1p, const half_t* __restrict__ zr1,
    const half_t* __restrict__ wt2, const float* __restrict__ b2,
    const half_t* __restrict__ th1, half_t* __restrict__ h2p,
    float* __restrict__ sums2)
{
    __shared__ __align__(16) char smem[37376];  // A-tile (25920) / obuf (36864) union; statsl @36864
    float* statsl = (float*)(smem + 36864);
    const int tile = blockIdx.x, s = blockIdx.y, n = blockIdx.z;
    const int tx = tile & 3, ty = tile >> 2, tid = threadIdx.x;
    const int l = tid & 63, wv = tid >> 6, l15 = l & 15, g = l >> 4;
    if (tid < 128) statsl[tid] = 0.f;

    const half_t* wb = wt2 + (size_t)s * 18432;
    half8 bfa[4], bfb[4];
    loadB2(bfa, wb, 0, l15, g);

    // stage 18x18x32 A-tile, 80B pixel stride, BN1-shift+relu applied
    const half_t* img = h1p + (size_t)(n * NS + s) * 135168;
    const half_t* zrow = zr1 + s * 2112;
    const int j = tid & 3;
    const half8 tshj = *(const half8*)(th1 + s * 32 + j * 8);
    for (int i = tid; i < 1296; i += 256) {
        int p = i >> 2;
        int py = p / 18, pxx = p - py * 18;
        int gy = ty * 16 + py - 1;
        const half_t* rp = ((unsigned)gy < 64u) ? (img + (size_t)gy * 2112) : zrow;
        half8 v = sr8(*(const half8*)(rp + (tx * 16 + pxx) * 32 + j * 8), tshj);
        *(half8*)(smem + p * 80 + j * 16) = v;
    }
    __syncthreads();

    f32x4 acc[4][4];
#pragma unroll
    for (int mt = 0; mt < 4; ++mt)
#pragma unroll
        for (int nt = 0; nt < 4; ++nt) acc[mt][nt] = (f32x4){0.f, 0.f, 0.f, 0.f};

#pragma unroll
    for (int tap = 0; tap < 9; ++tap) {
        if (tap & 1) {
            if (tap < 8) loadB2(bfa, wb, tap + 1, l15, g);
            comp2(acc, bfb, smem, tap, wv, l15, g);
        } else {
            if (tap < 8) loadB2(bfb, wb, tap + 1, l15, g);
            comp2(acc, bfa, smem, tap, wv, l15, g);
        }
    }

    // bias + per-channel stats
    float s1a[4], s2a[4];
#pragma unroll
    for (int nt = 0; nt < 4; ++nt) {
        float bias = b2[s * 64 + nt * 16 + l15];
        float s1 = 0.f, s2 = 0.f;
#pragma unroll
        for (int mt = 0; mt < 4; ++mt)
#pragma unroll
            for (int r = 0; r < 4; ++r) {
                float v = acc[mt][nt][r] + bias;
                acc[mt][nt][r] = v;
                s1 += v; s2 += v * v;
            }
        s1 += __shfl_xor(s1, 16); s1 += __shfl_xor(s1, 32);
        s2 += __shfl_xor(s2, 16); s2 += __shfl_xor(s2, 32);
        s1a[nt] = s1; s2a[nt] = s2;
    }
    if (l < 16) {
#pragma unroll
        for (int nt = 0; nt < 4; ++nt) {
            atomicAdd(&statsl[(nt * 16 + l15) * 2], s1a[nt]);
            atomicAdd(&statsl[(nt * 16 + l15) * 2 + 1], s2a[nt]);
        }
    }
    __syncthreads();                      // A reads + stats done -> reuse smem as obuf

    half_t* obuf = (half_t*)smem;         // [256 px][72]
#pragma unroll
    for (int mt = 0; mt < 4; ++mt)
#pragma unroll
        for (int nt = 0; nt < 4; ++nt)
#pragma unroll
            for (int r = 0; r < 4; ++r)
                obuf[((wv * 4 + mt) * 16 + g * 4 + r) * 72 + nt * 16 + l15] = (half_t)acc[mt][nt][r];
    __syncthreads();

    half_t* img2 = h2p + (size_t)(n * NS + s) * 270336;
    for (int i = tid; i < 2048; i += 256) {
        int p = i >> 3, cc = i & 7;
        int y = ty * 16 + (p >> 4), xp = tx * 16 + (p & 15) + 1;
        *(half8*)(img2 + (size_t)y * 4224 + xp * 64 + cc * 8) = *(const half8*)(obuf + p * 72 + cc * 8);
    }
    if (tid < 128)
        atomicAdd(&sums2[(s * 64 + (tid >> 1)) * 2 + (tid & 1)], statsl[tid]);
}

// ======== conv3: LDS A-tile (128B px stride, XOR-swizzled), B via register prefetch ========
__device__ __forceinline__ void loadB3(half8 bf[4][2], const half_t* wb, int tap, int l15, int g) {
#pragma unroll
    for (int nt = 0; nt < 4; ++nt) {
        const half_t* r = wb + (tap * 64 + nt * 16 + l15) * 64 + g * 8;
        bf[nt][0] = *(const half8*)(r);
        bf[nt][1] = *(const half8*)(r + 32);
    }
}

__device__ __forceinline__ void comp3(f32x4 acc[4][4], const half8 bf[4][2], const char* smem,
                                      int tap, int wv, int l15, int g) {
    const int ky = tap / 3, kx = tap - ky * 3;
#pragma unroll
    for (int mt = 0; mt < 4; ++mt) {
        int p = (wv * 4 + mt + ky) * 18 + l15 + kx;
        int base = p * 128, sw = (p & 7) << 4;
        half8 a0 = *(const half8*)(smem + base + ((g * 16) ^ sw));
        half8 a1 = *(const half8*)(smem + base + ((64 + g * 16) ^ sw));
#pragma unroll
        for (int nt = 0; nt < 4; ++nt) {
            acc[mt][nt] = __builtin_amdgcn_mfma_f32_16x16x32_f16(a0, bf[nt][0], acc[mt][nt], 0, 0, 0);
            acc[mt][nt] = __builtin_amdgcn_mfma_f32_16x16x32_f16(a1, bf[nt][1], acc[mt][nt], 0, 0, 0);
        }
    }
}

__global__ __launch_bounds__(256, 3) void conv3_k(
    const half_t* __restrict__ h2p, const half_t* __restrict__ zr2,
    const half_t* __restrict__ wt3, const float* __restrict__ b3,
    const half_t* __restrict__ th2, float* __restrict__ out,
    float* __restrict__ sums3)
{
    __shared__ __align__(16) char smem[41984];  // A-tile 41472 (324*128, swizzled) + statsl
    float* statsl = (float*)(smem + 41472);
    const int tile = blockIdx.x, s = blockIdx.y, n = blockIdx.z;
    const int tx = tile & 3, ty = tile >> 2, tid = threadIdx.x;
    const int l = tid & 63, wv = tid >> 6, l15 = l & 15, g = l >> 4;
    if (tid < 128) statsl[tid] = 0.f;

    const half_t* wb = wt3 + (size_t)s * 36864;
    half8 bfa[4][2], bfb[4][2];
    loadB3(bfa, wb, 0, l15, g);

    // stage 18x18x64 A-tile, 128B pixel stride XOR-swizzled, BN2-shift+relu applied
    const half_t* img = h2p + (size_t)(n * NS + s) * 270336;
    const half_t* zrow = zr2 + s * 4224;
    const int j = tid & 7;
    const half8 tshj = *(const half8*)(th2 + s * 64 + j * 8);
    for (int i = tid; i < 2592; i += 256) {
        int p = i >> 3;
        int py = p / 18, pxx = p - py * 18;
        int gy = ty * 16 + py - 1;
        const half_t* rp = ((unsigned)gy < 64u) ? (img + (size_t)gy * 4224) : zrow;
        half8 v = sr8(*(const half8*)(rp + (tx * 16 + pxx) * 64 + j * 8), tshj);
        *(half8*)(smem + p * 128 + ((j * 16) ^ ((p & 7) << 4))) = v;
    }
    __syncthreads();

    f32x4 acc[4][4];
#pragma unroll
    for (int mt = 0; mt < 4; ++mt)
#pragma unroll
        for (int nt = 0; nt < 4; ++nt) acc[mt][nt] = (f32x4){0.f, 0.f, 0.f, 0.f};

#pragma unroll
    for (int tap = 0; tap < 9; ++tap) {
        if (tap & 1) {
            if (tap < 8) loadB3(bfa, wb, tap + 1, l15, g);
            comp3(acc, bfb, smem, tap, wv, l15, g);
        } else {
            if (tap < 8) loadB3(bfb, wb, tap + 1, l15, g);
            comp3(acc, bfa, smem, tap, wv, l15, g);
        }
    }

    float s1a[4], s2a[4];
#pragma unroll
    for (int nt = 0; nt < 4; ++nt) {
        float bias = b3[s * 64 + nt * 16 + l15];
        float s1 = 0.f, s2 = 0.f;
#pragma unroll
        for (int mt = 0; mt < 4; ++mt)
#pragma unroll
            for (int r = 0; r < 4; ++r) {
                float v = acc[mt][nt][r] + bias;
                acc[mt][nt][r] = v;
                s1 += v; s2 += v * v;
            }
        s1 += __shfl_xor(s1, 16); s1 += __shfl_xor(s1, 32);
        s2 += __shfl_xor(s2, 16); s2 += __shfl_xor(s2, 32);
        s1a[nt] = s1; s2a[nt] = s2;
    }
    if (l < 16) {
#pragma unroll
        for (int nt = 0; nt < 4; ++nt) {
            atomicAdd(&statsl[(nt * 16 + l15) * 2], s1a[nt]);
            atomicAdd(&statsl[(nt * 16 + l15) * 2 + 1], s2a[nt]);
        }
    }

    // direct fp32 store into final layout out[s][n][c][y][x] (pre-BN3)
#pragma unroll
    for (int mt = 0; mt < 4; ++mt) {
        int gy = ty * 16 + wv * 4 + mt;
#pragma unroll
        for (int nt = 0; nt < 4; ++nt) {
            int c = nt * 16 + l15;
            *(f32x4*)(out + ((size_t)((s * NN + n) * 64 + c) * 64 + gy) * 64 + tx * 16 + g * 4) = acc[mt][nt];
        }
    }
    __syncthreads();
    if (tid < 128)
        atomicAdd(&sums3[(s * 64 + (tid >> 1)) * 2 + (tid & 1)], statsl[tid]);
}

// -------- final: in-place BN3+ReLU on d_out --------
__global__ __launch_bounds__(256) void final_k(float* __restrict__ out,
                                               const float* __restrict__ a3,
                                               const float* __restrict__ b3p)
{
    size_t i = ((size_t)blockIdx.x * 256 + threadIdx.x) * 4;
    int ch = (int)((i >> 12) & 63) + (int)(i >> 23) * 64; // c + s*64
    float sc = a3[ch], sh = b3p[ch];
    f32x4 v = *(f32x4*)(out + i);
#pragma unroll
    for (int r = 0; r < 4; ++r) v[r] = fmaxf(fmaf(sc, v[r], sh), 0.f);
    *(f32x4*)(out + i) = v;
}

extern "C" void kernel_launch(void* const* d_in, const int* in_sizes, int n_in,
                              void* d_out, int out_size, void* d_ws, size_t ws_size,
                              hipStream_t stream)
{
    const float* x   = (const float*)d_in[0];
    const float* w1  = (const float*)d_in[1];
    const float* b1  = (const float*)d_in[2];
    const float* g1  = (const float*)d_in[3];
    const float* be1 = (const float*)d_in[4];
    const float* w2  = (const float*)d_in[5];
    const float* b2  = (const float*)d_in[6];
    const float* g2  = (const float*)d_in[7];
    const float* be2 = (const float*)d_in[8];
    const float* w3  = (const float*)d_in[9];
    const float* b3  = (const float*)d_in[10];
    const float* g3  = (const float*)d_in[11];
    const float* be3 = (const float*)d_in[12];

    char* ws = (char*)d_ws;
    half_t* h1p = (half_t*)(ws + OFF_H1P);
    half_t* h2p = (half_t*)(ws + OFF_H2P);
    half_t* zr1 = (half_t*)(ws + OFF_ZR1);
    half_t* zr2 = (half_t*)(ws + OFF_ZR2);
    float*  wt1 = (float*)(ws + OFF_WT1);
    half_t* wt2 = (half_t*)(ws + OFF_WT2);
    half_t* wt3 = (half_t*)(ws + OFF_WT3);
    float*  sums = (float*)(ws + OFF_SUMS);
    float *s1v = sums, *s2v = sums + 1024, *s3v = sums + 3072;
    float*  prm = (float*)(ws + OFF_PRM);
    float *a1 = prm,        *b1p = prm + 512,  *t1 = prm + 1024;
    float *a2 = prm + 1536, *b2p = prm + 2560, *t2 = prm + 3584;
    float *a3 = prm + 4608, *b3p = prm + 5632, *t3 = prm + 6656;
    half_t* th = (half_t*)(ws + OFF_TH);
    half_t *th1 = th, *th2 = th + 512, *th3 = th + 1536;
    float* out = (float*)d_out;

    hipMemsetAsync(ws + OFF_SUMS, 0, 20480, stream);
    transform1_k<<<54, 256, 0, stream>>>(w1, wt1);
    dim3 grid(16, 16, 32); // (tile, seed, sample)
    conv1_k<<<grid, 256, 0, stream>>>(x, wt1, b1, h1p, s1v);
    bnparam_k<<<2, 256, 0, stream>>>(s1v, g1, be1, a1, b1p, t1, th1, 512);
    padfill_k<<<1041, 256, 0, stream>>>(h1p, zr1, t1, 32, 2, 135168L, 2112, 262144L, 266368L);
    wtrans2_k<<<1152, 256, 0, stream>>>(w2, a1, wt2);
    conv2_k<<<grid, 256, 0, stream>>>(h1p, zr1, wt2, b2, th1, h2p, s2v);
    bnparam_k<<<4, 256, 0, stream>>>(s2v, g2, be2, a2, b2p, t2, th2, 1024);
    padfill_k<<<2081, 256, 0, stream>>>(h2p, zr2, t2, 64, 3, 270336L, 4224, 524288L, 532736L);
    wtrans3_k<<<2304, 256, 0, stream>>>(w3, a2, wt3);
    conv3_k<<<grid, 256, 0, stream>>>(h2p, zr2, wt3, b3, th2, out, s3v);
    bnparam_k<<<4, 256, 0, stream>>>(s3v, g3, be3, a3, b3p, t3, th3, 1024);
    final_k<<<131072, 256, 0, stream>>>(out, a3, b3p);
}

// Round 4
// 877.049 us; speedup vs baseline: 1.3594x; 1.1420x over previous
//
#include <hip/hip_runtime.h>
#include <cstddef>
#include <cstdint>

typedef __attribute__((ext_vector_type(8))) _Float16 half8;
typedef __attribute__((ext_vector_type(4))) float f32x4;
typedef _Float16 half_t;

#define NS 16
#define NN 32

// ---------------- workspace layout (bytes) ----------------
static const size_t OFF_H1P = 0;
static const size_t OFF_H2P = 138412032ull;
static const size_t OFF_ZR1 = OFF_H2P + 276824064ull;   // 415236096
static const size_t OFF_ZR2 = OFF_ZR1 + 67584ull;       // 415303680
static const size_t OFF_WT1 = OFF_ZR2 + 135168ull;      // 415438848
static const size_t OFF_WT2 = OFF_WT1 + 55296ull;       // 415494144
static const size_t OFF_WT3 = OFF_WT2 + 589824ull;      // 416083968
static const size_t OFF_SUMS = OFF_WT3 + 1179648ull;    // 417263616
static const size_t OFF_PRM = OFF_SUMS + 20480ull;      // 417284096
static const size_t OFF_TH  = OFF_PRM + 30720ull;       // 417314816

static __device__ __forceinline__ half8 sr8(half8 v, half8 t) {
    half8 r = v + t;
    half8 z = {};
#if defined(__has_builtin) && __has_builtin(__builtin_elementwise_max)
    return __builtin_elementwise_max(r, z);
#else
#pragma unroll
    for (int j = 0; j < 8; ++j) r[j] = r[j] > (_Float16)0 ? r[j] : (_Float16)0;
    return r;
#endif
}

// -------- conv1 weights: oc-contiguous f32 --------
__global__ __launch_bounds__(256) void transform1_k(
    const float* __restrict__ w1, float* __restrict__ wt1)
{
    int idx = blockIdx.x * 256 + threadIdx.x;
    if (idx >= 13824) return;
    int o = idx & 31, tap = (idx >> 5) % 9, ic = (idx / 288) % 3, s = idx / 864;
    wt1[idx] = w1[((s * 32 + o) * 3 + ic) * 9 + tap];
}

// -------- conv2/conv3 weights: ic-contiguous f16, BN scale of previous layer folded --------
__global__ __launch_bounds__(256) void wtrans2_k(
    const float* __restrict__ w2, const float* __restrict__ a1, half_t* __restrict__ wt2)
{
    int idx = blockIdx.x * 256 + threadIdx.x;
    if (idx >= 294912) return;
    int ic = idx & 31, oc = (idx >> 5) & 63, tap = (idx >> 11) % 9, s = idx / 18432;
    wt2[idx] = (half_t)(w2[((s * 64 + oc) * 32 + ic) * 9 + tap] * a1[s * 32 + ic]);
}

__global__ __launch_bounds__(256) void wtrans3_k(
    const float* __restrict__ w3, const float* __restrict__ a2, half_t* __restrict__ wt3)
{
    int idx = blockIdx.x * 256 + threadIdx.x;
    if (idx >= 589824) return;
    int ic = idx & 63, oc = (idx >> 6) & 63, tap = (idx >> 12) % 9, s = idx / 36864;
    wt3[idx] = (half_t)(w3[((s * 64 + oc) * 64 + ic) * 9 + tap] * a2[s * 64 + ic]);
}

// -------- conv1: 3->32 per seed, fp32 vector math, writes x-padded h1p (pre-BN) + stats --------
__global__ __launch_bounds__(256) void conv1_k(
    const float* __restrict__ x, const float* __restrict__ wt1,
    const float* __restrict__ b1, half_t* __restrict__ h1p,
    float* __restrict__ sums1)
{
    __shared__ float smem[8512];
    float* xt = smem;
    float* bounce = smem;
    float* statsl = smem + 8448;
    const int tile = blockIdx.x, s = blockIdx.y, n = blockIdx.z;
    const int tx = tile & 3, ty = tile >> 2, tid = threadIdx.x;

    for (int i = tid; i < 972; i += 256) {
        int ic = i / 324, rem = i - ic * 324;
        int py = rem / 18, px = rem - py * 18;
        int gy = ty * 16 + py - 1, gx = tx * 16 + px - 1;
        float v = 0.f;
        if ((unsigned)gy < 64u && (unsigned)gx < 64u)
            v = x[(size_t)(((s * NN + n) * 3 + ic) * 64 + gy) * 64 + gx];
        xt[i] = v;
    }
    if (tid < 64) statsl[tid] = 0.f;
    __syncthreads();

    const int px = tid & 15, py = tid >> 4;
    float acc[32];
#pragma unroll
    for (int o = 0; o < 32; ++o) acc[o] = 0.f;
#pragma unroll
    for (int ic = 0; ic < 3; ++ic)
#pragma unroll
        for (int ky = 0; ky < 3; ++ky)
#pragma unroll
            for (int kx = 0; kx < 3; ++kx) {
                float v = xt[ic * 324 + (py + ky) * 18 + px + kx];
                const float* wp = wt1 + ((s * 3 + ic) * 9 + ky * 3 + kx) * 32;
#pragma unroll
                for (int o = 0; o < 32; ++o) acc[o] = fmaf(wp[o], v, acc[o]);
            }
    const float* bp = b1 + s * 32;
#pragma unroll
    for (int o = 0; o < 32; ++o) acc[o] += bp[o];

    const int gy1 = ty * 16 + py, gxp = tx * 16 + px + 1;
    half8* dst = (half8*)(h1p + (size_t)(n * NS + s) * 135168 + (size_t)(gy1 * 66 + gxp) * 32);
#pragma unroll
    for (int k = 0; k < 4; ++k) {
        half8 v8;
#pragma unroll
        for (int j = 0; j < 8; ++j) v8[j] = (half_t)acc[k * 8 + j];
        dst[k] = v8;
    }
    __syncthreads();
#pragma unroll
    for (int o = 0; o < 32; ++o) bounce[tid * 33 + o] = acc[o];
    __syncthreads();
    {
        const int oc = tid & 31, grp = tid >> 5;
        float s1 = 0.f, s2 = 0.f;
#pragma unroll 4
        for (int j = 0; j < 32; ++j) {
            float v = bounce[(grp * 32 + j) * 33 + oc];
            s1 += v; s2 += v * v;
        }
        atomicAdd(&statsl[oc * 2], s1);
        atomicAdd(&statsl[oc * 2 + 1], s2);
    }
    __syncthreads();
    if (tid < 64)
        atomicAdd(&sums1[(s * 32 + (tid >> 1)) * 2 + (tid & 1)], statsl[tid]);
}

// -------- sums -> scale a, shift b, pre-act shift t = b/a (and f16 copy) --------
__global__ void bnparam_k(const float* __restrict__ sums, const float* __restrict__ g,
                          const float* __restrict__ be, float* __restrict__ a,
                          float* __restrict__ b, float* __restrict__ t,
                          half_t* __restrict__ th, int C)
{
    int ch = blockIdx.x * 256 + threadIdx.x;
    if (ch >= C) return;
    const float inv = 1.f / 131072.f;     // N*H*W = 32*64*64
    float mean = sums[ch * 2] * inv;
    float var = sums[ch * 2 + 1] * inv - mean * mean;
    float sc = g[ch] * rsqrtf(var + 1e-5f);
    a[ch] = sc;
    float bb = be[ch] - mean * sc;
    b[ch] = bb;
    float tt = bb / sc;
    t[ch] = tt;
    th[ch] = (half_t)tt;
}

// -------- fill pad columns + pad row with q = -(t+1), so relu(q + t) == 0 --------
__global__ __launch_bounds__(256) void padfill_k(
    half_t* __restrict__ img, half_t* __restrict__ zrow, const float* __restrict__ t,
    int C, int c8shift, long imgstride, int rowstride, long tot_cols, long tot)
{
    long idx = (long)blockIdx.x * 256 + threadIdx.x;
    if (idx >= tot) return;
    const int nc8m = (1 << c8shift) - 1;
    if (idx < tot_cols) {
        int c8 = (int)idx & nc8m; long r = idx >> c8shift;
        int side = (int)r & 1; r >>= 1;
        int y = (int)r & 63; r >>= 6;
        int si = (int)(r & 15); int ni = (int)(r >> 4);
        half8 q;
#pragma unroll
        for (int j = 0; j < 8; ++j) q[j] = (half_t)(-(t[si * C + c8 * 8 + j] + 1.0f));
        *(half8*)(img + (long)(ni * NS + si) * imgstride + (long)y * rowstride +
                  (side ? 65 : 0) * C + c8 * 8) = q;
    } else {
        long r2 = idx - tot_cols;
        int c8 = (int)r2 & nc8m; r2 >>= c8shift;
        int xx = (int)(r2 % 66); int si = (int)(r2 / 66);
        half8 q;
#pragma unroll
        for (int j = 0; j < 8; ++j) q[j] = (half_t)(-(t[si * C + c8 * 8 + j] + 1.0f));
        *(half8*)(zrow + ((long)(si * 66 + xx)) * C + c8 * 8) = q;
    }
}

// ======== conv2: LDS A-tile (80B px stride), B via register prefetch ========
__device__ __forceinline__ void loadB2(half8 bf[4], const half_t* wb, int tap, int l15, int g) {
#pragma unroll
    for (int nt = 0; nt < 4; ++nt)
        bf[nt] = *(const half8*)(wb + (tap * 64 + nt * 16 + l15) * 32 + g * 8);
}

__device__ __forceinline__ void comp2(f32x4 acc[4][4], const half8 bf[4], const char* smem,
                                      int tap, int wv, int l15, int g) {
    const int ky = tap / 3, kx = tap - ky * 3;
#pragma unroll
    for (int mt = 0; mt < 4; ++mt) {
        int p = (wv * 4 + mt + ky) * 18 + l15 + kx;
        half8 av = *(const half8*)(smem + p * 80 + g * 16);
#pragma unroll
        for (int nt = 0; nt < 4; ++nt)
            acc[mt][nt] = __builtin_amdgcn_mfma_f32_16x16x32_f16(av, bf[nt], acc[mt][nt], 0, 0, 0);
    }
}

__global__ __launch_bounds__(256, 3) void conv2_k(
    const half_t* __restrict__ h1p, const half_t* __restrict__ zr1,
    const half_t* __restrict__ wt2, const float* __restrict__ b2,
    const half_t* __restrict__ th1, half_t* __restrict__ h2p,
    float* __restrict__ sums2)
{
    __shared__ __align__(16) char smem[37376];  // A-tile (25920) / obuf (36864) union; statsl @36864
    float* statsl = (float*)(smem + 36864);
    const int tile = blockIdx.x, s = blockIdx.y, n = blockIdx.z;
    const int tx = tile & 3, ty = tile >> 2, tid = threadIdx.x;
    const int l = tid & 63, wv = tid >> 6, l15 = l & 15, g = l >> 4;
    if (tid < 128) statsl[tid] = 0.f;

    const half_t* wb = wt2 + (size_t)s * 18432;
    half8 bfa[4], bfb[4];
    loadB2(bfa, wb, 0, l15, g);

    // stage 18x18x32 A-tile, 80B pixel stride, BN1-shift+relu applied
    const half_t* img = h1p + (size_t)(n * NS + s) * 135168;
    const half_t* zrow = zr1 + s * 2112;
    const int j = tid & 3;
    const half8 tshj = *(const half8*)(th1 + s * 32 + j * 8);
    for (int i = tid; i < 1296; i += 256) {
        int p = i >> 2;
        int py = p / 18, pxx = p - py * 18;
        int gy = ty * 16 + py - 1;
        const half_t* rp = ((unsigned)gy < 64u) ? (img + (size_t)gy * 2112) : zrow;
        half8 v = sr8(*(const half8*)(rp + (tx * 16 + pxx) * 32 + j * 8), tshj);
        *(half8*)(smem + p * 80 + j * 16) = v;
    }
    __syncthreads();

    f32x4 acc[4][4];
#pragma unroll
    for (int mt = 0; mt < 4; ++mt)
#pragma unroll
        for (int nt = 0; nt < 4; ++nt) acc[mt][nt] = (f32x4){0.f, 0.f, 0.f, 0.f};

#pragma unroll
    for (int tap = 0; tap < 9; ++tap) {
        if (tap & 1) {
            if (tap < 8) loadB2(bfa, wb, tap + 1, l15, g);
            comp2(acc, bfb, smem, tap, wv, l15, g);
        } else {
            if (tap < 8) loadB2(bfb, wb, tap + 1, l15, g);
            comp2(acc, bfa, smem, tap, wv, l15, g);
        }
    }

    // bias + per-channel stats
    float s1a[4], s2a[4];
#pragma unroll
    for (int nt = 0; nt < 4; ++nt) {
        float bias = b2[s * 64 + nt * 16 + l15];
        float s1 = 0.f, s2 = 0.f;
#pragma unroll
        for (int mt = 0; mt < 4; ++mt)
#pragma unroll
            for (int r = 0; r < 4; ++r) {
                float v = acc[mt][nt][r] + bias;
                acc[mt][nt][r] = v;
                s1 += v; s2 += v * v;
            }
        s1 += __shfl_xor(s1, 16); s1 += __shfl_xor(s1, 32);
        s2 += __shfl_xor(s2, 16); s2 += __shfl_xor(s2, 32);
        s1a[nt] = s1; s2a[nt] = s2;
    }
    if (l < 16) {
#pragma unroll
        for (int nt = 0; nt < 4; ++nt) {
            atomicAdd(&statsl[(nt * 16 + l15) * 2], s1a[nt]);
            atomicAdd(&statsl[(nt * 16 + l15) * 2 + 1], s2a[nt]);
        }
    }
    __syncthreads();                      // A reads + stats done -> reuse smem as obuf

    half_t* obuf = (half_t*)smem;         // [256 px][72]
#pragma unroll
    for (int mt = 0; mt < 4; ++mt)
#pragma unroll
        for (int nt = 0; nt < 4; ++nt)
#pragma unroll
            for (int r = 0; r < 4; ++r)
                obuf[((wv * 4 + mt) * 16 + g * 4 + r) * 72 + nt * 16 + l15] = (half_t)acc[mt][nt][r];
    __syncthreads();

    half_t* img2 = h2p + (size_t)(n * NS + s) * 270336;
    for (int i = tid; i < 2048; i += 256) {
        int p = i >> 3, cc = i & 7;
        int y = ty * 16 + (p >> 4), xp = tx * 16 + (p & 15) + 1;
        *(half8*)(img2 + (size_t)y * 4224 + xp * 64 + cc * 8) = *(const half8*)(obuf + p * 72 + cc * 8);
    }
    if (tid < 128)
        atomicAdd(&sums2[(s * 64 + (tid >> 1)) * 2 + (tid & 1)], statsl[tid]);
}

// ======== conv3: tile 64x4, 512 threads, coalesced full-row fp32 stores ========
__device__ __forceinline__ void loadB3(half8 bf[2][2], const half_t* wb, int tap,
                                       int och, int l15, int g) {
#pragma unroll
    for (int nt = 0; nt < 2; ++nt) {
        const half_t* r = wb + (tap * 64 + och * 32 + nt * 16 + l15) * 64 + g * 8;
        bf[nt][0] = *(const half8*)(r);
        bf[nt][1] = *(const half8*)(r + 32);
    }
}

__device__ __forceinline__ void comp3(f32x4 acc[4][2], const half8 bf[2][2], const char* smem,
                                      int tap, int wy, int l15, int g) {
    const int ky = tap / 3, kx = tap - ky * 3;
#pragma unroll
    for (int mt = 0; mt < 4; ++mt) {
        int p = (wy + ky) * 66 + mt * 16 + l15 + kx;
        int base = p * 128, sw = (p & 7) << 4;
        half8 a0 = *(const half8*)(smem + base + ((g * 16) ^ sw));
        half8 a1 = *(const half8*)(smem + base + ((64 + g * 16) ^ sw));
#pragma unroll
        for (int nt = 0; nt < 2; ++nt) {
            acc[mt][nt] = __builtin_amdgcn_mfma_f32_16x16x32_f16(a0, bf[nt][0], acc[mt][nt], 0, 0, 0);
            acc[mt][nt] = __builtin_amdgcn_mfma_f32_16x16x32_f16(a1, bf[nt][1], acc[mt][nt], 0, 0, 0);
        }
    }
}

__global__ __launch_bounds__(512, 4) void conv3_k(
    const half_t* __restrict__ h2p, const half_t* __restrict__ zr2,
    const half_t* __restrict__ wt3, const float* __restrict__ b3,
    const half_t* __restrict__ th2, float* __restrict__ out,
    float* __restrict__ sums3)
{
    __shared__ __align__(16) char smem[51200];  // A-tile 396*128 swizzled + statsl @50688
    float* statsl = (float*)(smem + 50688);
    const int ty = blockIdx.x, s = blockIdx.y, n = blockIdx.z;
    const int tid = threadIdx.x;
    const int l = tid & 63, w = tid >> 6, l15 = l & 15, g = l >> 4;
    const int wy = w & 3, och = w >> 2;
    if (tid < 128) statsl[tid] = 0.f;

    const half_t* wb = wt3 + (size_t)s * 36864;
    half8 bfa[2][2], bfb[2][2];
    loadB3(bfa, wb, 0, och, l15, g);

    // stage 6 rows x 66 cols x 64 ch (x-halo already in padded layout; y-halo via zrow)
    const half_t* img = h2p + (size_t)(n * NS + s) * 270336;
    const half_t* zrow = zr2 + s * 4224;
    const int j = tid & 7;
    const half8 tshj = *(const half8*)(th2 + s * 64 + j * 8);
    for (int i = tid; i < 3168; i += 512) {
        int p = i >> 3;                   // c8 == j (invariant: stride 512 keeps i&7)
        int row = p / 66, col = p - row * 66;
        int gy = ty * 4 + row - 1;
        const half_t* rp = ((unsigned)gy < 64u) ? (img + (size_t)gy * 4224) : zrow;
        half8 v = sr8(*(const half8*)(rp + col * 64 + j * 8), tshj);
        *(half8*)(smem + p * 128 + ((j * 16) ^ ((p & 7) << 4))) = v;
    }
    __syncthreads();

    f32x4 acc[4][2];
#pragma unroll
    for (int mt = 0; mt < 4; ++mt)
#pragma unroll
        for (int nt = 0; nt < 2; ++nt) acc[mt][nt] = (f32x4){0.f, 0.f, 0.f, 0.f};

#pragma unroll
    for (int tap = 0; tap < 9; ++tap) {
        if (tap & 1) {
            if (tap < 8) loadB3(bfa, wb, tap + 1, och, l15, g);
            comp3(acc, bfb, smem, tap, wy, l15, g);
        } else {
            if (tap < 8) loadB3(bfb, wb, tap + 1, och, l15, g);
            comp3(acc, bfa, smem, tap, wy, l15, g);
        }
    }

    float s1a[2], s2a[2];
#pragma unroll
    for (int nt = 0; nt < 2; ++nt) {
        float bias = b3[s * 64 + och * 32 + nt * 16 + l15];
        float s1 = 0.f, s2 = 0.f;
#pragma unroll
        for (int mt = 0; mt < 4; ++mt)
#pragma unroll
            for (int r = 0; r < 4; ++r) {
                float v = acc[mt][nt][r] + bias;
                acc[mt][nt][r] = v;
                s1 += v; s2 += v * v;
            }
        s1 += __shfl_xor(s1, 16); s1 += __shfl_xor(s1, 32);
        s2 += __shfl_xor(s2, 16); s2 += __shfl_xor(s2, 32);
        s1a[nt] = s1; s2a[nt] = s2;
    }
    if (l < 16) {
#pragma unroll
        for (int nt = 0; nt < 2; ++nt) {
            atomicAdd(&statsl[(och * 32 + nt * 16 + l15) * 2], s1a[nt]);
            atomicAdd(&statsl[(och * 32 + nt * 16 + l15) * 2 + 1], s2a[nt]);
        }
    }

    // coalesced fp32 store: wave owns full 64-wide row for its 32 channels (pre-BN3)
    const int gy = ty * 4 + wy;
#pragma unroll
    for (int mt = 0; mt < 4; ++mt)
#pragma unroll
        for (int nt = 0; nt < 2; ++nt) {
            int c = och * 32 + nt * 16 + l15;
            *(f32x4*)(out + ((size_t)((s * NN + n) * 64 + c) * 64 + gy) * 64 + mt * 16 + g * 4) = acc[mt][nt];
        }
    __syncthreads();
    if (tid < 128)
        atomicAdd(&sums3[(s * 64 + (tid >> 1)) * 2 + (tid & 1)], statsl[tid]);
}

// -------- final: in-place BN3+ReLU on d_out --------
__global__ __launch_bounds__(256) void final_k(float* __restrict__ out,
                                               const float* __restrict__ a3,
                                               const float* __restrict__ b3p)
{
    size_t i = ((size_t)blockIdx.x * 256 + threadIdx.x) * 4;
    int ch = (int)((i >> 12) & 63) + (int)(i >> 23) * 64; // c + s*64
    float sc = a3[ch], sh = b3p[ch];
    f32x4 v = *(f32x4*)(out + i);
#pragma unroll
    for (int r = 0; r < 4; ++r) v[r] = fmaxf(fmaf(sc, v[r], sh), 0.f);
    *(f32x4*)(out + i) = v;
}

extern "C" void kernel_launch(void* const* d_in, const int* in_sizes, int n_in,
                              void* d_out, int out_size, void* d_ws, size_t ws_size,
                              hipStream_t stream)
{
    const float* x   = (const float*)d_in[0];
    const float* w1  = (const float*)d_in[1];
    const float* b1  = (const float*)d_in[2];
    const float* g1  = (const float*)d_in[3];
    const float* be1 = (const float*)d_in[4];
    const float* w2  = (const float*)d_in[5];
    const float* b2  = (const float*)d_in[6];
    const float* g2  = (const float*)d_in[7];
    const float* be2 = (const float*)d_in[8];
    const float* w3  = (const float*)d_in[9];
    const float* b3  = (const float*)d_in[10];
    const float* g3  = (const float*)d_in[11];
    const float* be3 = (const float*)d_in[12];

    char* ws = (char*)d_ws;
    half_t* h1p = (half_t*)(ws + OFF_H1P);
    half_t* h2p = (half_t*)(ws + OFF_H2P);
    half_t* zr1 = (half_t*)(ws + OFF_ZR1);
    half_t* zr2 = (half_t*)(ws + OFF_ZR2);
    float*  wt1 = (float*)(ws + OFF_WT1);
    half_t* wt2 = (half_t*)(ws + OFF_WT2);
    half_t* wt3 = (half_t*)(ws + OFF_WT3);
    float*  sums = (float*)(ws + OFF_SUMS);
    float *s1v = sums, *s2v = sums + 1024, *s3v = sums + 3072;
    float*  prm = (float*)(ws + OFF_PRM);
    float *a1 = prm,        *b1p = prm + 512,  *t1 = prm + 1024;
    float *a2 = prm + 1536, *b2p = prm + 2560, *t2 = prm + 3584;
    float *a3 = prm + 4608, *b3p = prm + 5632, *t3 = prm + 6656;
    half_t* th = (half_t*)(ws + OFF_TH);
    half_t *th1 = th, *th2 = th + 512, *th3 = th + 1536;
    float* out = (float*)d_out;

    hipMemsetAsync(ws + OFF_SUMS, 0, 20480, stream);
    transform1_k<<<54, 256, 0, stream>>>(w1, wt1);
    dim3 grid(16, 16, 32); // (tile, seed, sample)
    conv1_k<<<grid, 256, 0, stream>>>(x, wt1, b1, h1p, s1v);
    bnparam_k<<<2, 256, 0, stream>>>(s1v, g1, be1, a1, b1p, t1, th1, 512);
    padfill_k<<<1041, 256, 0, stream>>>(h1p, zr1, t1, 32, 2, 135168L, 2112, 262144L, 266368L);
    wtrans2_k<<<1152, 256, 0, stream>>>(w2, a1, wt2);
    conv2_k<<<grid, 256, 0, stream>>>(h1p, zr1, wt2, b2, th1, h2p, s2v);
    bnparam_k<<<4, 256, 0, stream>>>(s2v, g2, be2, a2, b2p, t2, th2, 1024);
    padfill_k<<<2081, 256, 0, stream>>>(h2p, zr2, t2, 64, 3, 270336L, 4224, 524288L, 532736L);
    wtrans3_k<<<2304, 256, 0, stream>>>(w3, a2, wt3);
    dim3 grid3(16, 16, 32); // (y-tile, seed, sample)
    conv3_k<<<grid3, 512, 0, stream>>>(h2p, zr2, wt3, b3, th2, out, s3v);
    bnparam_k<<<4, 256, 0, stream>>>(s3v, g3, be3, a3, b3p, t3, th3, 1024);
    final_k<<<131072, 256, 0, stream>>>(out, a3, b3p);
}